// Round 10
// baseline (205.881 us; speedup 1.0000x reference)
//
#include <hip/hip_runtime.h>
#include <hip/hip_bf16.h>

#define Hh 50

typedef __attribute__((ext_vector_type(8))) short bf16x8;
typedef __attribute__((ext_vector_type(4))) float f32x4;

static __device__ __forceinline__ short b16(float x) {
    return __builtin_bit_cast(short, __float2bfloat16(x));
}
// convert 8 contiguous f32 to a bf16x8 MFMA fragment
static __device__ __forceinline__ bf16x8 cvt8(const float* p) {
    f32x4 a = *(const f32x4*)p;
    f32x4 b = *(const f32x4*)(p + 4);
    bf16x8 r;
    r[0] = b16(a[0]); r[1] = b16(a[1]); r[2] = b16(a[2]); r[3] = b16(a[3]);
    r[4] = b16(b[0]); r[5] = b16(b[1]); r[6] = b16(b[2]); r[7] = b16(b[3]);
    return r;
}

// -------- Kernel 0: pack wh_w into 16x16x32 B-fragment order --------
// whpk[((p*8+ks)*64+l)*8+j] = bf16(wh_w[p*16+(l&15)][ks*32+(l>>4)*8+j])
__global__ __launch_bounds__(256) void k_prep(const float* __restrict__ w,
                                              short* __restrict__ o) {
    int t = (int)blockIdx.x * 256 + threadIdx.x;   // 0..8191
    int p  = t >> 9;
    int ks = (t >> 6) & 7;
    int l  = t & 63;
    int col = p * 16 + (l & 15);
    int k   = ks * 32 + (l >> 4) * 8;
    bf16x8 v = cvt8(w + (size_t)col * 256 + k);
    *(bf16x8*)(o + (size_t)t * 8) = v;
}

// ---------------- Kernel 1: wcplus[4096][256] (f32) = cur @ wc_w^T + wc_b + wh_b ------
__global__ __launch_bounds__(64) void k_wc(const float* __restrict__ cur,
                                           const float* __restrict__ wcw,
                                           const float* __restrict__ wcb,
                                           const float* __restrict__ whb,
                                           float* __restrict__ out) {
    int l = threadIdx.x;
    int m0 = (int)(blockIdx.x >> 2) * 16;
    int ntb = (int)(blockIdx.x & 3) * 4;
    int lk = (l >> 4) * 8;

    bf16x8 Af[8];
#pragma unroll
    for (int k = 0; k < 8; k++)
        Af[k] = cvt8(cur + (size_t)(m0 + (l & 15)) * 256 + k * 32 + lk);

#pragma unroll
    for (int nt = 0; nt < 4; nt++) {
        int col = (ntb + nt) * 16 + (l & 15);
        f32x4 a = {0.f, 0.f, 0.f, 0.f};
#pragma unroll
        for (int k = 0; k < 8; k++) {
            bf16x8 Bf = cvt8(wcw + (size_t)col * 256 + k * 32 + lk);
            a = __builtin_amdgcn_mfma_f32_16x16x32_bf16(Af[k], Bf, a, 0, 0, 0);
        }
        float bias = wcb[col] + whb[col];
        int row = m0 + (l >> 4) * 4;
#pragma unroll
        for (int r = 0; r < 4; r++)
            out[(size_t)(row + r) * 256 + col] = a[r] + bias;
    }
}

// ---------------- Kernel 2: flat GEMM + fused sigmoid/qt epilogue -> alpha ----------
// M = B*Hh*S = 204800 flattened hist rows. Block = 128 consecutive rows (contiguous
// 128 KB stage), 1024 thr = 16 waves. Wave w owns col-panel w (16 cols): Bf[8] = 32
// VGPR resident. A (hist) from swizzled LDS. alpha[row] = qtb + sum_col qt*sigmoid(.).
__global__ __launch_bounds__(1024, 4)
void k_alpha(const float* __restrict__ hist,
             const float* __restrict__ wcplus,
             const short* __restrict__ whpk,
             const float* __restrict__ qtw,
             const float* __restrict__ qtb,
             float* __restrict__ alphaWS) {
    __shared__ __align__(16) char histA[128 * 512];   // swizzled bf16 [row][256]
    __shared__ float alphaP[16][128];

    int tid = threadIdx.x;
    int l = tid & 63;
    int w = tid >> 6;                  // 0..15 = col panel
    int bh = (int)(blockIdx.x >> 2);   // (b*50 + h)
    int s0 = (int)(blockIdx.x & 3) * 128;
    int b = bh / Hh;

    // stage 128 contiguous rows (128 KB f32 -> 64 KB bf16, swizzled)
    const float* hsrc = hist + ((size_t)bh * 512 + s0) * 256;
#pragma unroll
    for (int i = 0; i < 4; i++) {
        int c = tid + i * 1024;        // 0..4095
        int r = c >> 5, g = c & 31;
        bf16x8 v = cvt8(hsrc + (size_t)c * 8);
        *(bf16x8*)(&histA[r * 512 + ((g ^ (r & 15)) << 4)]) = v;
    }

    // B panel: 8 x 1KB contiguous wave-loads (32 VGPR)
    bf16x8 Bf[8];
    const short* wqp = whpk + ((size_t)(w * 8) * 64 + l) * 8;
#pragma unroll
    for (int ks = 0; ks < 8; ks++)
        Bf[ks] = *(const bf16x8*)(wqp + ks * 512);

    int col = w * 16 + (l & 15);
    float qv = qtw[col];
    const float* wcp = wcplus + ((size_t)(b * 512 + s0) + (l >> 4) * 4) * 256 + col;
    __syncthreads();

#pragma unroll 1
    for (int msub = 0; msub < 8; msub++) {
        int rA = msub * 16 + (l & 15);
        f32x4 acc = {0.f, 0.f, 0.f, 0.f};
#pragma unroll
        for (int ks = 0; ks < 8; ks++) {
            int g = ks * 4 + (l >> 4);
            bf16x8 Ah = *(const bf16x8*)(&histA[rA * 512 + ((g ^ (rA & 15)) << 4)]);
            acc = __builtin_amdgcn_mfma_f32_16x16x32_bf16(Ah, Bf[ks], acc, 0, 0, 0);
        }
        // epilogue: bias from wcplus, sigmoid, qt, 16-lane column reduce
#pragma unroll
        for (int r = 0; r < 4; r++) {
            float bias = wcp[(size_t)(msub * 16 + r) * 256];
            float v = acc[r] + bias;
            float pal = qv * __builtin_amdgcn_rcpf(1.0f + __expf(-v));
            pal += __shfl_xor(pal, 1);
            pal += __shfl_xor(pal, 2);
            pal += __shfl_xor(pal, 4);
            pal += __shfl_xor(pal, 8);
            if ((l & 15) == 0)
                alphaP[w][msub * 16 + (l >> 4) * 4 + r] = pal;
        }
    }
    __syncthreads();

    if (tid < 128) {
        float a = qtb[0];
#pragma unroll
        for (int p = 0; p < 16; p++) a += alphaP[p][tid];
        alphaWS[(size_t)blockIdx.x * 128 + tid] = a;
    }
}

// ---------------- Kernel 3: hsum[b,s,:] = sum_h alpha[b,h,s] * hist[b,h,s,:] ----------
// Block = (b, 8 consecutive s): per h one contiguous 8 KB read. alpha pre-staged in LDS.
__global__ __launch_bounds__(256, 8)
void k_hsum(const float* __restrict__ hist,
            const float* __restrict__ alphaWS,
            float* __restrict__ hsum) {
    __shared__ float al[Hh * 8];
    int tid = threadIdx.x;
    int x = (int)blockIdx.x;          // b*64 + sc
    int b = x >> 6, s0 = (x & 63) * 8;

    for (int t = tid; t < Hh * 8; t += 256) {
        int h = t >> 3, j = t & 7;
        al[t] = alphaWS[(size_t)(b * Hh + h) * 512 + s0 + j];
    }
    __syncthreads();

    int sidx = tid >> 5;
    int d = (tid & 31) * 8;
    const float* hp = hist + ((size_t)(b * Hh) * 512 + s0 + sidx) * 256 + d;
    f32x4 a0 = {0.f, 0.f, 0.f, 0.f}, a1 = {0.f, 0.f, 0.f, 0.f};
#pragma unroll 2
    for (int h = 0; h < Hh; h++) {
        f32x4 v0 = *(const f32x4*)(hp + (size_t)h * 512 * 256);
        f32x4 v1 = *(const f32x4*)(hp + (size_t)h * 512 * 256 + 4);
        float a = al[h * 8 + sidx];
#pragma unroll
        for (int j = 0; j < 4; j++) { a0[j] += a * v0[j]; a1[j] += a * v1[j]; }
    }
    float* op = hsum + ((size_t)b * 512 + s0 + sidx) * 256 + d;
    *(f32x4*)op = a0;
    *(f32x4*)(op + 4) = a1;
}

// ---------------- Kernel 4: out[4096][128] (f32) = [cur, hsum] @ wf_w^T + wf_b --------
__global__ __launch_bounds__(64) void k_wf(const float* __restrict__ cur,
                                           const float* __restrict__ hsum,
                                           const float* __restrict__ wfw,
                                           const float* __restrict__ wfb,
                                           float* __restrict__ out) {
    int l = threadIdx.x;
    int m0 = (int)(blockIdx.x >> 1) * 16;
    int ntb = (int)(blockIdx.x & 1) * 4;
    int lk = (l >> 4) * 8;

    f32x4 acc[4];
#pragma unroll
    for (int nt = 0; nt < 4; nt++) acc[nt] = (f32x4){0.f, 0.f, 0.f, 0.f};

#pragma unroll
    for (int k = 0; k < 16; k++) {
        int row = m0 + (l & 15);
        bf16x8 Af;
        if (k < 8)
            Af = cvt8(cur + (size_t)row * 256 + k * 32 + lk);
        else
            Af = cvt8(hsum + (size_t)row * 256 + (k - 8) * 32 + lk);
#pragma unroll
        for (int nt = 0; nt < 4; nt++) {
            int col = (ntb + nt) * 16 + (l & 15);
            bf16x8 Bf = cvt8(wfw + (size_t)col * 512 + k * 32 + lk);
            acc[nt] = __builtin_amdgcn_mfma_f32_16x16x32_bf16(Af, Bf, acc[nt], 0, 0, 0);
        }
    }
#pragma unroll
    for (int nt = 0; nt < 4; nt++) {
        int col = (ntb + nt) * 16 + (l & 15);
        float bias = wfb[col];
        int row = m0 + (l >> 4) * 4;
#pragma unroll
        for (int r = 0; r < 4; r++)
            out[(size_t)(row + r) * 128 + col] = acc[nt][r] + bias;
    }
}

extern "C" void kernel_launch(void* const* d_in, const int* in_sizes, int n_in,
                              void* d_out, int out_size, void* d_ws, size_t ws_size,
                              hipStream_t stream) {
    const float* hist = (const float*)d_in[0];
    const float* cur  = (const float*)d_in[1];
    const float* wc_w = (const float*)d_in[2];
    const float* wc_b = (const float*)d_in[3];
    const float* wh_w = (const float*)d_in[4];
    const float* wh_b = (const float*)d_in[5];
    const float* qt_w = (const float*)d_in[6];
    const float* qt_b = (const float*)d_in[7];
    const float* wf_w = (const float*)d_in[8];
    const float* wf_b = (const float*)d_in[9];

    float* wc_ws   = (float*)d_ws;                                          // 4 MB
    float* hsum    = (float*)((char*)d_ws + ((size_t)4 << 20));             // 4 MB
    short* whpk    = (short*)((char*)d_ws + ((size_t)8 << 20));             // 128 KB
    float* alphaWS = (float*)((char*)d_ws + ((size_t)8 << 20) + 131072);    // 800 KB

    k_prep<<<32, 256, 0, stream>>>(wh_w, whpk);
    k_wc<<<1024, 64, 0, stream>>>(cur, wc_w, wc_b, wh_b, wc_ws);
    k_alpha<<<1600, 1024, 0, stream>>>(hist, wc_ws, whpk, qt_w, qt_b, alphaWS);
    k_hsum<<<512, 256, 0, stream>>>(hist, alphaWS, hsum);
    k_wf<<<512, 64, 0, stream>>>(cur, hsum, wf_w, wf_b, (float*)d_out);
}